// Round 5
// baseline (12.247 us; speedup 1.0000x reference)
//
#include <hip/hip_runtime.h>
#include <hip/hip_bf16.h>

#define BT_DEPTH 20
#define BT_NDIMS 128

// Row-local shift-right add via DPP row_shr (0-filled, bound_ctrl=true).
// After ctrl 0x111,0x112,0x114,0x118 lane (row*16+15) holds the 16-lane sum.
template <int CTRL>
__device__ __forceinline__ float dpp_row_shr_add(float v) {
    int sh = __builtin_amdgcn_update_dpp(0, __float_as_int(v), CTRL, 0xF, 0xF, true);
    return v + __int_as_float(sh);
}

// 256 threads = 4 waves x 4 groups of 16 lanes = 16 level-groups; 8 dims/lane.
// Pass 0 covers levels 0..15, pass 1 covers 16..20 (invalid groups clamp to the
// leaf row; result discarded). All loads (leaf + both passes) issue up-front.
// Per-level reduce = 4-deep DPP chain. One barrier + 4-entry LDS combine.
__global__ __launch_bounds__(256) void BinaryTree_18734647345500_kernel(
    const float* __restrict__ W,
    const int* __restrict__ v_j_idx,
    const int* __restrict__ u_k_idx,
    float* __restrict__ out)
{
    __shared__ float pp[4];

    const int tid  = threadIdx.x;
    const int wave = tid >> 6;
    const int lane = tid & 63;
    const int d    = lane & 15;         // dim chunk (8 floats)
    const int G    = (wave << 2) | (lane >> 4);  // global level-group 0..15

    const int v = v_j_idx[0];
    const int u = u_k_idx[0];

    const long long leaf = (long long)v + ((1 << BT_DEPTH) - 1);
    const unsigned  t    = (unsigned)u + (1u << BT_DEPTH);

    // Issue ALL loads first (leaf + 2 passes), independent -> one round-trip.
    const float* xrow = W + leaf * BT_NDIMS + d * 8;
    const float4 x0 = *(const float4*)(xrow);
    const float4 x1 = *(const float4*)(xrow + 4);

    float4 r0[2], r1[2];
    #pragma unroll
    for (int p = 0; p < 2; ++p) {
        const int l = p * 16 + G;
        const int shift = (l <= BT_DEPTH) ? (BT_DEPTH - l) : 0;  // clamp -> leaf row
        const long long node = (long long)(t >> shift) - 1;
        const float* row = W + node * (long long)BT_NDIMS + d * 8;
        r0[p] = *(const float4*)(row);
        r1[p] = *(const float4*)(row + 4);
    }

    // Reduce + sigmoid factors. qp = prod over this group's valid levels of
    // (1 + exp(-z_l)); held in lane d==15 of each group.
    float qp = 1.0f;
    #pragma unroll
    for (int p = 0; p < 2; ++p) {
        const int l = p * 16 + G;
        float s = r0[p].x * x0.x + r0[p].y * x0.y + r0[p].z * x0.z + r0[p].w * x0.w
                + r1[p].x * x1.x + r1[p].y * x1.y + r1[p].z * x1.z + r1[p].w * x1.w;
        s = dpp_row_shr_add<0x111>(s);
        s = dpp_row_shr_add<0x112>(s);
        s = dpp_row_shr_add<0x114>(s);
        s = dpp_row_shr_add<0x118>(s);
        const float q = 1.0f + __expf(-s);
        if (l <= BT_DEPTH && d == 15) qp *= q;
    }

    // Wave-level combine of the 4 group leaders (lanes 15/31/47/63).
    const float r15 = __uint_as_float(__builtin_amdgcn_readlane(__float_as_uint(qp), 15));
    const float r31 = __uint_as_float(__builtin_amdgcn_readlane(__float_as_uint(qp), 31));
    const float r47 = __uint_as_float(__builtin_amdgcn_readlane(__float_as_uint(qp), 47));
    const float r63 = __uint_as_float(__builtin_amdgcn_readlane(__float_as_uint(qp), 63));
    if (lane == 0) pp[wave] = r15 * r31 * r47 * r63;
    __syncthreads();

    if (tid == 0) {
        out[0] = 1.0f / (pp[0] * pp[1] * pp[2] * pp[3]);
    }
}

extern "C" void kernel_launch(void* const* d_in, const int* in_sizes, int n_in,
                              void* d_out, int out_size, void* d_ws, size_t ws_size,
                              hipStream_t stream) {
    const float* W   = (const float*)d_in[0];
    const int*   vj  = (const int*)d_in[1];
    const int*   uk  = (const int*)d_in[2];
    float*       out = (float*)d_out;

    hipLaunchKernelGGL(BinaryTree_18734647345500_kernel,
                       dim3(1), dim3(256), 0, stream,
                       W, vj, uk, out);
}